// Round 13
// baseline (45135.834 us; speedup 1.0000x reference)
//
#include <hip/hip_runtime.h>
#include <hip/hip_cooperative_groups.h>
#include <cmath>

namespace cg = cooperative_groups;

#define BB   64      // batch
#define DD   512     // data dim
#define UU   768     // units
#define GG   2304    // 3*UU
#define TIN  64
#define TOUT 64
#define NBLK 256

// LDS layout (f32x4 units): 9 rows per matrix, row = cc*3+gate
#define OFF_WX0 0          // 9 x 128 f4
#define OFF_WH0 1152       // 9 x 192
#define OFF_WX1 2880
#define OFF_WH1 4608
#define OFF_WX2 6336
#define OFF_WH2 8064
#define OFF_H2S 9792       // dense h2 staging: 196 f4 (padded: +1 per 48)
#define LDS_F4  9988
#define LDS_BYTES    (LDS_F4 * 16)   // 159,808 B <= 163,840
#define LDS_BYTES_CG (9792 * 16)

typedef float f32x4 __attribute__((ext_vector_type(4)));
typedef float f32x2 __attribute__((ext_vector_type(2)));
typedef int   i32x4 __attribute__((ext_vector_type(4)));

// CK-style raw buffer intrinsics (compiler-tracked loads/stores; SRD bounds-check)
__device__ f32x4 buf_ld4(i32x4 srsrc, int voffset, int soffset, int aux) __asm("llvm.amdgcn.raw.buffer.load.v4f32");
__device__ float buf_ld1(i32x4 srsrc, int voffset, int soffset, int aux) __asm("llvm.amdgcn.raw.buffer.load.f32");
__device__ void  buf_st1(float data, i32x4 srsrc, int voffset, int soffset, int aux) __asm("llvm.amdgcn.raw.buffer.store.f32");

#define AUX_SC 17   // CPol SC0|SC1: bypass L1/L2, access the coherence point

__device__ __forceinline__ i32x4 make_srd(const void* base, unsigned bytes) {
  unsigned long long a = (unsigned long long)base;
  i32x4 r;
  r.x = (int)(a & 0xffffffffull);
  r.y = (int)(a >> 32);
  r.z = (int)bytes;
  r.w = 0x00020000;
  return r;
}

__device__ __forceinline__ int wsoff(const float* base, const float* q) {
  return (int)((const char*)q - (const char*)base);
}

struct P {
  const float* inputs;
  const float* Wx[3];
  const float* Wh[3];
  const float* bi[3];
  const float* br[3];
  const float* h0[3];
  const float* Wd;
  const float* bd;
  const float* mean;
  const float* stdv;
  const float* WxT[3];
  const float* WhT[3];
  const float* WdT;
  float* out;
  float* ws;
  unsigned* bar;
};

__device__ __forceinline__ float sigm(float a) { return 1.0f / (1.0f + expf(-a)); }

__device__ __forceinline__ f32x2 pkfma(f32x2 a, f32x2 b, f32x2 c) {
  return __builtin_elementwise_fma(a, b, c);
}
__device__ __forceinline__ void dot4p(f32x4 a, f32x4 b, f32x2& acc) {
  f32x2 alo = { a.x, a.y }, ahi = { a.z, a.w };
  f32x2 blo = { b.x, b.y }, bhi = { b.z, b.w };
  acc = pkfma(alo, blo, acc);
  acc = pkfma(ahi, bhi, acc);
}
__device__ __forceinline__ float dot4(f32x4 a, f32x4 b, float acc) {
  acc = fmaf(a.x, b.x, acc);
  acc = fmaf(a.y, b.y, acc);
  acc = fmaf(a.z, b.z, acc);
  acc = fmaf(a.w, b.w, acc);
  return acc;
}

// ---- fence-free two-level grid barrier (R11-proven) ----
__device__ __forceinline__ void gridbar(unsigned* bar, unsigned& epoch) {
  asm volatile("s_waitcnt vmcnt(0)" ::: "memory");
  __syncthreads();
  if (threadIdx.x == 0) {
    const unsigned next = epoch + 1;
    unsigned* leaf = bar + (blockIdx.x & 15) * 32;
    unsigned* root = bar + 512;
    unsigned* gen  = bar + 544;
    unsigned lold = __hip_atomic_fetch_add(leaf, 1u, __ATOMIC_RELAXED, __HIP_MEMORY_SCOPE_AGENT);
    if (lold == next * 16u - 1u) {
      unsigned rold = __hip_atomic_fetch_add(root, 1u, __ATOMIC_RELAXED, __HIP_MEMORY_SCOPE_AGENT);
      if (rold == next * 16u - 1u) {
        __hip_atomic_store(gen, next, __ATOMIC_RELAXED, __HIP_MEMORY_SCOPE_AGENT);
      } else {
        while (__hip_atomic_load(gen, __ATOMIC_RELAXED, __HIP_MEMORY_SCOPE_AGENT) < next)
          __builtin_amdgcn_s_sleep(1);
      }
    } else {
      while (__hip_atomic_load(gen, __ATOMIC_RELAXED, __HIP_MEMORY_SCOPE_AGENT) < next)
        __builtin_amdgcn_s_sleep(1);
    }
    asm volatile("" ::: "memory");
  }
  epoch += 1;
  __syncthreads();
}

__global__ void bar_init_kernel(unsigned* bar) {
  for (int i = threadIdx.x; i < 1024; i += 256)
    __hip_atomic_store(bar + i, 0u, __ATOMIC_RELAXED, __HIP_MEMORY_SCOPE_AGENT);
}

// ---------------- tiled transpose: dst[c][r] = src[r][c] ----------------
__global__ __launch_bounds__(256) void transpose_kernel(
    const float* __restrict__ src, float* __restrict__ dst, int R, int C) {
  __shared__ float tile[32][33];
  const int bx = blockIdx.x * 32;
  const int by = blockIdx.y * 32;
  const int tx = threadIdx.x;
  const int ty = threadIdx.y;
  #pragma unroll
  for (int i = 0; i < 32; i += 8)
    tile[ty + i][tx] = src[(size_t)(by + ty + i) * C + (bx + tx)];
  __syncthreads();
  #pragma unroll
  for (int i = 0; i < 32; i += 8)
    dst[(size_t)(bx + ty + i) * R + (by + tx)] = tile[tx][ty + i];
}

// ---- load a 24-f4 coherent row slice into a register array ----
__device__ __forceinline__ void pref_load24(i32x4 srd, int rowoff, int kq, f32x4* b) {
  #pragma unroll
  for (int t = 0; t < 24; ++t)
    b[t] = buf_ld4(srd, rowoff + (t * 8 + kq) * 16, 0, AUX_SC);
}

// ---- consume a register slice against LDS weights (t ascending) ----
template<int KX4>
__device__ __forceinline__ void matdot9_reg24(const f32x4* b, const f32x4* __restrict__ w,
                                              int kq, f32x2* __restrict__ acc) {
  #pragma unroll
  for (int t = 0; t < 24; ++t) {
    #pragma unroll
    for (int r = 0; r < 9; ++r)
      dot4p(b[t], w[r * KX4 + t * 8 + kq], acc[r]);
  }
}

// ---- 9-row dot, live coherent loads in rolling groups of 8 ----
template<int NT, int KX4>
__device__ __forceinline__ void matdot9_buf(i32x4 srd, int rowoff,
                                            const f32x4* __restrict__ w,
                                            int kq, f32x2* __restrict__ acc) {
  f32x4 g0[8], g1[8];
  #pragma unroll
  for (int u = 0; u < 8; ++u)
    g0[u] = buf_ld4(srd, rowoff + (u * 8 + kq) * 16, 0, AUX_SC);
  #pragma unroll
  for (int u = 0; u < 8; ++u)
    g1[u] = buf_ld4(srd, rowoff + ((8 + u) * 8 + kq) * 16, 0, AUX_SC);
  #pragma unroll
  for (int u = 0; u < 8; ++u) {
    #pragma unroll
    for (int r = 0; r < 9; ++r)
      dot4p(g0[u], w[r * KX4 + u * 8 + kq], acc[r]);
  }
  if constexpr (NT == 24) {
    #pragma unroll
    for (int u = 0; u < 8; ++u)
      g0[u] = buf_ld4(srd, rowoff + ((16 + u) * 8 + kq) * 16, 0, AUX_SC);
  }
  #pragma unroll
  for (int u = 0; u < 8; ++u) {
    #pragma unroll
    for (int r = 0; r < 9; ++r)
      dot4p(g1[u], w[r * KX4 + (8 + u) * 8 + kq], acc[r]);
  }
  if constexpr (NT == 24) {
    #pragma unroll
    for (int u = 0; u < 8; ++u) {
      #pragma unroll
      for (int r = 0; r < 9; ++r)
        dot4p(g0[u], w[r * KX4 + (16 + u) * 8 + kq], acc[r]);
    }
  }
}

// ---- plain cached path (read-only inputs tensor) ----
template<int NT, int KX4>
__device__ __forceinline__ void matdot9_pl(const float* __restrict__ rowbase,
                                           const f32x4* __restrict__ w,
                                           int kq, f32x2* __restrict__ acc) {
  const f32x4* xv = (const f32x4*)rowbase;
  #pragma unroll 2
  for (int t = 0; t < NT; ++t) {
    const int idx = t * 8 + kq;
    f32x4 v = xv[idx];
    #pragma unroll
    for (int r = 0; r < 9; ++r) dot4p(v, w[r * KX4 + idx], acc[r]);
  }
}

// ---- hprev loads, hoisted to cell entry (latency hides under matdots) ----
__device__ __forceinline__ void load_hprev(i32x4 srd, const float* wsbase,
                                           const float* hrow, int c0, int kq,
                                           float* hp3) {
  hp3[0] = hp3[1] = hp3[2] = 0.f;
  if (kq == 0) {
    const int ho = wsoff(wsbase, hrow + c0);
    hp3[0] = buf_ld1(srd, ho,     0, AUX_SC);
    hp3[1] = buf_ld1(srd, ho + 4, 0, AUX_SC);
    hp3[2] = buf_ld1(srd, ho + 8, 0, AUX_SC);
  }
}

__device__ __forceinline__ void pk_reduce9(const f32x2* p, float* s) {
  #pragma unroll
  for (int r = 0; r < 9; ++r) s[r] = p[r].x + p[r].y;
}

// ---- gate epilogue: reduce, gates, write-through h stores ----
// hnrow must be the PER-BATCH row pointer (caller applies +b*UU).
__device__ __forceinline__ void gru_fin(
    const float* wsbase, i32x4 srd,
    f32x2* __restrict__ axp, f32x2* __restrict__ ahp,
    const float* __restrict__ bi, const float* __restrict__ br,
    const float* __restrict__ hp3, float* __restrict__ hnrow,
    int c0, int kq)
{
  float ax[9], ah[9];
  pk_reduce9(axp, ax);
  pk_reduce9(ahp, ah);
  #pragma unroll
  for (int r = 0; r < 9; ++r) {
    ax[r] += __shfl_xor(ax[r], 1, 8); ax[r] += __shfl_xor(ax[r], 2, 8); ax[r] += __shfl_xor(ax[r], 4, 8);
    ah[r] += __shfl_xor(ah[r], 1, 8); ah[r] += __shfl_xor(ah[r], 2, 8); ah[r] += __shfl_xor(ah[r], 4, 8);
  }
  if (kq == 0) {
    const int hno = wsoff(wsbase, hnrow + c0);
    #pragma unroll
    for (int cc = 0; cc < 3; ++cc) {
      const int c = c0 + cc;
      float z  = sigm(ax[cc*3+0] + bi[c]        + ah[cc*3+0] + br[c]);
      float rr = sigm(ax[cc*3+1] + bi[c+UU]     + ah[cc*3+1] + br[c+UU]);
      float hc = tanhf(ax[cc*3+2] + bi[c+2*UU]  + rr * (ah[cc*3+2] + br[c+2*UU]));
      buf_st1(z * hp3[cc] + (1.f - z) * hc, srd, hno + cc * 4, 0, AUX_SC);
    }
  }
}

// ---- warmup-edge cell: x live-or-cached, h live ----
template<int NT, int KX4, bool XSC>
__device__ __forceinline__ void gru_cell_live(
    const float* wsbase, i32x4 srd,
    const float* __restrict__ x, int xstride,
    const f32x4* __restrict__ wx, const f32x4* __restrict__ wh,
    const float* __restrict__ bi, const float* __restrict__ br,
    const float* __restrict__ hp, float* __restrict__ hn,
    int c0, int b, int kq)
{
  const float* xrow = x + (size_t)b * xstride;
  const float* hrow = hp + (size_t)b * UU;
  float hp3[3];
  load_hprev(srd, wsbase, hrow, c0, kq, hp3);
  f32x2 axp[9], ahp[9];
  #pragma unroll
  for (int r = 0; r < 9; ++r) { axp[r] = (f32x2)0.f; ahp[r] = (f32x2)0.f; }
  if constexpr (XSC) matdot9_buf<NT, KX4>(srd, wsoff(wsbase, xrow), wx, kq, axp);
  else               matdot9_pl<NT, KX4>(xrow, wx, kq, axp);
  matdot9_buf<24, 192>(srd, wsoff(wsbase, hrow), wh, kq, ahp);
  gru_fin(wsbase, srd, axp, ahp, bi, br, hp3, hn + (size_t)b * UU, c0, kq);
}

// ---- fused warmup diagonal (all 3 layers active): each h-slice loaded ONCE,
// consumed by two accumulators. ALL row pointers (read AND write) are
// per-batch rows (+b*UU applied by the caller). ----
__device__ __forceinline__ void warm_fused(
    const float* wsbase, i32x4 srd, const P& p,
    const float* __restrict__ xin,           // inputs row (+b*TIN*DD + d*DD)
    const f32x4* wx0, const f32x4* wh0, const f32x4* wx1, const f32x4* wh1,
    const f32x4* wx2, const f32x4* wh2,
    const float* h0row, const float* h1row, const float* h2row,
    float* hn0row, float* hn1row, float* hn2row,
    int c0, int b, int kq)
{
  float hp0[3], hp1[3], hp2[3];
  load_hprev(srd, wsbase, h0row, c0, kq, hp0);
  load_hprev(srd, wsbase, h1row, c0, kq, hp1);
  load_hprev(srd, wsbase, h2row, c0, kq, hp2);

  f32x4 H[24];
  // phase 1: H = h0 slice -> L1's x-acc and L0's h-acc; L0's x from inputs
  pref_load24(srd, wsoff(wsbase, h0row), kq, H);
  f32x2 ax1[9];
  #pragma unroll
  for (int r = 0; r < 9; ++r) ax1[r] = (f32x2)0.f;
  matdot9_reg24<192>(H, wx1, kq, ax1);
  {
    f32x2 ax0[9], ah0[9];
    #pragma unroll
    for (int r = 0; r < 9; ++r) { ax0[r] = (f32x2)0.f; ah0[r] = (f32x2)0.f; }
    matdot9_reg24<192>(H, wh0, kq, ah0);
    matdot9_pl<16, 128>(xin, wx0, kq, ax0);
    gru_fin(wsbase, srd, ax0, ah0, p.bi[0], p.br[0], hp0, hn0row, c0, kq);
  }
  // phase 2: H = h1 slice -> L2's x-acc and L1's h-acc
  pref_load24(srd, wsoff(wsbase, h1row), kq, H);
  f32x2 ax2[9];
  #pragma unroll
  for (int r = 0; r < 9; ++r) ax2[r] = (f32x2)0.f;
  matdot9_reg24<192>(H, wx2, kq, ax2);
  {
    f32x2 ah1[9];
    #pragma unroll
    for (int r = 0; r < 9; ++r) ah1[r] = (f32x2)0.f;
    matdot9_reg24<192>(H, wh1, kq, ah1);
    gru_fin(wsbase, srd, ax1, ah1, p.bi[1], p.br[1], hp1, hn1row, c0, kq);
  }
  // phase 3: H = h2 slice -> L2's h-acc
  pref_load24(srd, wsoff(wsbase, h2row), kq, H);
  {
    f32x2 ah2[9];
    #pragma unroll
    for (int r = 0; r < 9; ++r) ah2[r] = (f32x2)0.f;
    matdot9_reg24<192>(H, wh2, kq, ah2);
    gru_fin(wsbase, srd, ax2, ah2, p.bi[2], p.br[2], hp2, hn2row, c0, kq);
  }
}

// ---- dense: stage padded h2-row (SC) into LDS; xbuf write is sc store ----
__device__ __forceinline__ void dense_buf(
    const float* wsbase, i32x4 srd,
    const float* __restrict__ h2, const float* __restrict__ WdT,
    const float* __restrict__ bd, const float* __restrict__ mean,
    const float* __restrict__ stdv, float* __restrict__ out,
    float* __restrict__ xbuf, f32x4* __restrict__ ldsh2,
    int s, int blk, int tid)
{
  const int bb = blk >> 2;
  const float* hrow = h2 + (size_t)bb * UU;
  if (tid < 192) {
    ldsh2[tid + tid / 48] = buf_ld4(srd, wsoff(wsbase, hrow) + tid * 16, 0, AUX_SC);
  }
  __syncthreads();
  const int dc = (blk & 3) * 128 + (tid >> 2);
  const int kq = tid & 3;
  const f32x4* hv = ldsh2 + kq * 49;
  const f32x4* w  = (const f32x4*)(WdT + (size_t)dc * UU) + kq * 48;
  f32x2 acc2 = (f32x2)0.f;
  #pragma unroll 4
  for (int i = 0; i < 48; ++i) dot4p(hv[i], w[i], acc2);
  float acc = acc2.x + acc2.y;
  acc += __shfl_xor(acc, 1, 4);
  acc += __shfl_xor(acc, 2, 4);
  if (kq == 0) {
    float val = acc + bd[dc];
    out[((size_t)bb * TOUT + s) * DD + dc] = val;
    buf_st1((val - mean[dc]) / stdv[dc], srd,
            wsoff(wsbase, xbuf + (size_t)bb * DD + dc), 0, AUX_SC);
  }
}

// ---- LDS weight staging (both kernels) ----
__device__ __forceinline__ void stage_lds(f32x4* lds4, const P& p, int c0, int tid) {
  const float* srcs[6] = { p.WxT[0], p.WhT[0], p.WxT[1], p.WhT[1], p.WxT[2], p.WhT[2] };
  const int    Ks[6]   = { DD, UU, UU, UU, UU, UU };
  const int    offs[6] = { OFF_WX0, OFF_WH0, OFF_WX1, OFF_WH1, OFF_WX2, OFF_WH2 };
  for (int m = 0; m < 6; ++m) {
    const int K4 = Ks[m] >> 2;
    for (int r = 0; r < 9; ++r) {
      const int cc = r / 3, g = r % 3;
      const f32x4* src = (const f32x4*)(srcs[m] + (size_t)(g * UU + c0 + cc) * Ks[m]);
      f32x4* dst = lds4 + offs[m] + (size_t)r * K4;
      for (int i = tid; i < K4; i += 512) dst[i] = src[i];
    }
  }
}

// =================== main: write-through exchange, retained-slice AR, fused warmup ===================
__global__ __launch_bounds__(512, 2) void gru_ar_buf(P p) {
  extern __shared__ f32x4 lds4[];
  const int tid = threadIdx.x, blk = blockIdx.x;
  const int b = tid >> 3, kq = tid & 7, c0 = blk * 3;

  float* hbuf = p.ws;                    // [2 slots][3 layers][BB][UU]
  float* xbuf = p.ws + 6 * BB * UU;      // [BB][DD]
  unsigned epoch = 0;
  const i32x4 srd = make_srd(p.ws, (unsigned)((6 * BB * UU + BB * DD) * sizeof(float)));

  stage_lds(lds4, p, c0, tid);

  // init: layer j initial state -> slot j&1 (write-through sc stores)
  for (int i = blk * 512 + tid; i < 3 * BB * UU; i += NBLK * 512) {
    int j = i / (BB * UU);
    int rem = i - j * (BB * UU);
    int u = rem % UU;
    int idx = (int)(((j & 1) * 3 + j) * (BB * UU) + rem);
    buf_st1(p.h0[j][u], srd, idx * 4, 0, AUX_SC);
  }
  gridbar(p.bar, epoch);

  const f32x4* wx0 = lds4 + OFF_WX0;
  const f32x4* wh0 = lds4 + OFF_WH0;
  const f32x4* wx1 = lds4 + OFF_WX1;
  const f32x4* wh1 = lds4 + OFF_WH1;
  const f32x4* wx2 = lds4 + OFF_WX2;
  const f32x4* wh2 = lds4 + OFF_WH2;
  f32x4* ldsh2 = lds4 + OFF_H2S;

  #define HBASE(sl, j) (hbuf + ((size_t)(sl) * 3 + (j)) * BB * UU)

  // ---- warmup: wavefront diagonals; fused when all 3 layers active ----
  for (int d = 0; d < TIN + 2; ++d) {
    const int rs = d & 1, wsl = rs ^ 1;
    if (d >= 2 && d <= TIN - 1) {
      warm_fused(p.ws, srd, p,
                 p.inputs + (size_t)b * (TIN * DD) + (size_t)d * DD,
                 wx0, wh0, wx1, wh1, wx2, wh2,
                 HBASE(rs, 0) + (size_t)b * UU,
                 HBASE(rs, 1) + (size_t)b * UU,
                 HBASE(rs, 2) + (size_t)b * UU,
                 HBASE(wsl, 0) + (size_t)b * UU,    // FIX: write rows are per-batch
                 HBASE(wsl, 1) + (size_t)b * UU,
                 HBASE(wsl, 2) + (size_t)b * UU,
                 c0, b, kq);
    } else {
      if (d < TIN) {
        gru_cell_live<16, 128, false>(p.ws, srd, p.inputs + (size_t)d * DD, TIN * DD,
                                      wx0, wh0, p.bi[0], p.br[0],
                                      HBASE(rs, 0), HBASE(wsl, 0), c0, b, kq);
      }
      if (d >= 1 && d <= TIN) {
        gru_cell_live<24, 192, true>(p.ws, srd, HBASE(rs, 0), UU,
                                     wx1, wh1, p.bi[1], p.br[1],
                                     HBASE(rs, 1), HBASE(wsl, 1), c0, b, kq);
      }
      if (d >= 2 && d <= TIN + 1) {
        gru_cell_live<24, 192, true>(p.ws, srd, HBASE(rs, 1), UU,
                                     wx2, wh2, p.bi[2], p.br[2],
                                     HBASE(rs, 2), HBASE(wsl, 2), c0, b, kq);
      }
    }
    gridbar(p.bar, epoch);
  }

  // pred0 (h2 final warmup state in slot 0) + bootstrap hA = h0-state slice
  f32x4 hA[24], pfX[24];
  dense_buf(p.ws, srd, HBASE(0, 2), p.WdT, p.bd, p.mean, p.stdv,
            p.out, xbuf, ldsh2, 0, blk, tid);
  pref_load24(srd, wsoff(p.ws, HBASE(0, 0) + (size_t)b * UU), kq, hA);
  gridbar(p.bar, epoch);

  // ---- autoregressive: 4 barriers/step; hA retained (B -> next A),
  // pfX = 1-region-ahead prefetch (h1 at A, h2 at B) ----
  for (int s = 0; s < TOUT - 1; ++s) {
    const int rs = s & 1;
    { // A: L0@s — h from hA, x live from xbuf
      const float* hrow = HBASE(rs, 0) + (size_t)b * UU;
      float hp3[3];
      load_hprev(srd, p.ws, hrow, c0, kq, hp3);
      f32x2 axp[9], ahp[9];
      #pragma unroll
      for (int r = 0; r < 9; ++r) { axp[r] = (f32x2)0.f; ahp[r] = (f32x2)0.f; }
      matdot9_reg24<192>(hA, wh0, kq, ahp);
      matdot9_buf<16, 128>(srd, wsoff(p.ws, xbuf + (size_t)b * DD), wx0, kq, axp);
      gru_fin(p.ws, srd, axp, ahp, p.bi[0], p.br[0], hp3,
              HBASE(rs ^ 1, 0) + (size_t)b * UU, c0, kq);
      pref_load24(srd, wsoff(p.ws, HBASE(rs ^ 1, 1) + (size_t)b * UU), kq, pfX); // h1(s-1)
      gridbar(p.bar, epoch);
    }
    { // B: L1@s — h from pfX; x = h0(s) loaded into hA (RETAINED for A@s+1)
      const float* hrow = HBASE(rs ^ 1, 1) + (size_t)b * UU;
      float hp3[3];
      load_hprev(srd, p.ws, hrow, c0, kq, hp3);
      f32x2 axp[9], ahp[9];
      #pragma unroll
      for (int r = 0; r < 9; ++r) { axp[r] = (f32x2)0.f; ahp[r] = (f32x2)0.f; }
      matdot9_reg24<192>(pfX, wh1, kq, ahp);                               // consume pfX (freed)
      pref_load24(srd, wsoff(p.ws, HBASE(rs ^ 1, 0) + (size_t)b * UU), kq, hA); // x = h0(s), retain
      matdot9_reg24<192>(hA, wx1, kq, axp);
      gru_fin(p.ws, srd, axp, ahp, p.bi[1], p.br[1], hp3,
              HBASE(rs, 1) + (size_t)b * UU, c0, kq);
      pref_load24(srd, wsoff(p.ws, HBASE(rs, 2) + (size_t)b * UU), kq, pfX); // h2(s-1)
      gridbar(p.bar, epoch);
    }
    { // C: L2@s — h from pfX, x = h1(s) live
      const float* hrow = HBASE(rs, 2) + (size_t)b * UU;
      float hp3[3];
      load_hprev(srd, p.ws, hrow, c0, kq, hp3);
      f32x2 axp[9], ahp[9];
      #pragma unroll
      for (int r = 0; r < 9; ++r) { axp[r] = (f32x2)0.f; ahp[r] = (f32x2)0.f; }
      matdot9_reg24<192>(pfX, wh2, kq, ahp);
      matdot9_buf<24, 192>(srd, wsoff(p.ws, HBASE(rs, 1) + (size_t)b * UU), wx2, kq, axp);
      gru_fin(p.ws, srd, axp, ahp, p.bi[2], p.br[2], hp3,
              HBASE(rs ^ 1, 2) + (size_t)b * UU, c0, kq);
      gridbar(p.bar, epoch);
    }
    dense_buf(p.ws, srd, HBASE(rs ^ 1, 2), p.WdT, p.bd, p.mean, p.stdv,
              p.out, xbuf, ldsh2, s + 1, blk, tid);
    gridbar(p.bar, epoch);
  }
  #undef HBASE
}

// =================== fallback: cg-sync kernel (proven) ===================
template<int NX4T, int KX4>
__device__ __forceinline__ void gru_cell_lds(
    const float* __restrict__ x, int xstride,
    const f32x4* __restrict__ wx, const f32x4* __restrict__ wh,
    const float* __restrict__ bi, const float* __restrict__ br,
    const float* __restrict__ hp, float* __restrict__ hn,
    int c0, int b, int kq)
{
  float ax[9], ah[9];
  #pragma unroll
  for (int r = 0; r < 9; ++r) { ax[r] = 0.f; ah[r] = 0.f; }
  const f32x4* xv = (const f32x4*)(x + (size_t)b * xstride);
  #pragma unroll 2
  for (int t = 0; t < NX4T; ++t) {
    const int idx = t * 8 + kq;
    f32x4 v = xv[idx];
    #pragma unroll
    for (int r = 0; r < 9; ++r) ax[r] = dot4(v, wx[r * KX4 + idx], ax[r]);
  }
  const f32x4* hv = (const f32x4*)(hp + (size_t)b * UU);
  #pragma unroll 2
  for (int t = 0; t < 24; ++t) {
    const int idx = t * 8 + kq;
    f32x4 v = hv[idx];
    #pragma unroll
    for (int r = 0; r < 9; ++r) ah[r] = dot4(v, wh[r * 192 + idx], ah[r]);
  }
  #pragma unroll
  for (int r = 0; r < 9; ++r) {
    ax[r] += __shfl_xor(ax[r], 1, 8); ax[r] += __shfl_xor(ax[r], 2, 8); ax[r] += __shfl_xor(ax[r], 4, 8);
    ah[r] += __shfl_xor(ah[r], 1, 8); ah[r] += __shfl_xor(ah[r], 2, 8); ah[r] += __shfl_xor(ah[r], 4, 8);
  }
  #pragma unroll
  for (int cc = 0; cc < 3; ++cc) {
    const int c = c0 + cc;
    float z  = sigm(ax[cc*3+0] + bi[c]        + ah[cc*3+0] + br[c]);
    float rr = sigm(ax[cc*3+1] + bi[c+UU]     + ah[cc*3+1] + br[c+UU]);
    float hc = tanhf(ax[cc*3+2] + bi[c+2*UU]  + rr * (ah[cc*3+2] + br[c+2*UU]));
    float hprev = hp[(size_t)b * UU + c];
    if (kq == 0) hn[(size_t)b * UU + c] = z * hprev + (1.f - z) * hc;
  }
}

__device__ __forceinline__ void dense_t(
    const float* __restrict__ h2, const float* __restrict__ WdT,
    const float* __restrict__ bd, const float* __restrict__ mean,
    const float* __restrict__ stdv, float* __restrict__ out,
    float* __restrict__ xbuf, int s, int blk, int tid)
{
  const int o  = blk * 128 + (tid >> 2);
  const int bb = o >> 9;
  const int dc = o & 511;
  const int kq = tid & 3;
  const f32x4* hv = (const f32x4*)(h2 + (size_t)bb * UU) + kq * 48;
  const f32x4* w  = (const f32x4*)(WdT + (size_t)dc * UU) + kq * 48;
  float acc = 0.f;
  #pragma unroll 4
  for (int i = 0; i < 48; ++i) acc = dot4(hv[i], w[i], acc);
  acc += __shfl_xor(acc, 1, 4);
  acc += __shfl_xor(acc, 2, 4);
  if (kq == 0) {
    float val = acc + bd[dc];
    out[((size_t)bb * TOUT + s) * DD + dc] = val;
    xbuf[(size_t)bb * DD + dc] = (val - mean[dc]) / stdv[dc];
  }
}

__global__ __launch_bounds__(512, 2) void gru_ar_cg(P p) {
  cg::grid_group grid = cg::this_grid();
  extern __shared__ f32x4 lds4[];
  const int tid = threadIdx.x, blk = blockIdx.x;
  const int b = tid >> 3, kq = tid & 7, c0 = blk * 3;
  float* hbuf = p.ws;
  float* xbuf = p.ws + 6 * BB * UU;
  stage_lds(lds4, p, c0, tid);
  for (int i = blk * 512 + tid; i < 3 * BB * UU; i += NBLK * 512) {
    int j = i / (BB * UU);
    int u = i % UU;
    hbuf[i] = p.h0[j][u];
  }
  grid.sync();
  const f32x4* wx0 = lds4 + OFF_WX0; const f32x4* wh0 = lds4 + OFF_WH0;
  const f32x4* wx1 = lds4 + OFF_WX1; const f32x4* wh1 = lds4 + OFF_WH1;
  const f32x4* wx2 = lds4 + OFF_WX2; const f32x4* wh2 = lds4 + OFF_WH2;
  for (int t = 0; t < TIN + TOUT - 1; ++t) {
    const int pr = t & 1, pw = pr ^ 1;
    #pragma unroll 1
    for (int j = 0; j < 3; ++j) {
      const float* x; int xstride;
      if (j == 0) {
        if (t < TIN) { x = p.inputs + (size_t)t * DD; xstride = TIN * DD; }
        else         { x = xbuf;                       xstride = DD; }
      } else {
        x = hbuf + ((size_t)pw * 3 + (j - 1)) * BB * UU; xstride = UU;
      }
      const float* hp = hbuf + ((size_t)pr * 3 + j) * BB * UU;
      float*       hn = hbuf + ((size_t)pw * 3 + j) * BB * UU;
      if (j == 0)      gru_cell_lds<16, 128>(x, xstride, wx0, wh0, p.bi[0], p.br[0], hp, hn, c0, b, kq);
      else if (j == 1) gru_cell_lds<24, 192>(x, xstride, wx1, wh1, p.bi[1], p.br[1], hp, hn, c0, b, kq);
      else             gru_cell_lds<24, 192>(x, xstride, wx2, wh2, p.bi[2], p.br[2], hp, hn, c0, b, kq);
      grid.sync();
    }
    if (t >= TIN - 1) {
      const int s = t - (TIN - 1);
      const float* h2 = hbuf + ((size_t)pw * 3 + 2) * BB * UU;
      dense_t(h2, p.WdT, p.bd, p.mean, p.stdv, p.out, xbuf, s, blk, tid);
      grid.sync();
    }
  }
}

extern "C" void kernel_launch(void* const* d_in, const int* in_sizes, int n_in,
                              void* d_out, int out_size, void* d_ws, size_t ws_size,
                              hipStream_t stream) {
  P p;
  p.inputs = (const float*)d_in[0];
  int k = 1;
  for (int j = 0; j < 3; ++j) {
    p.Wx[j] = (const float*)d_in[k++];
    p.Wh[j] = (const float*)d_in[k++];
    p.bi[j] = (const float*)d_in[k++];
    p.br[j] = (const float*)d_in[k++];
    p.h0[j] = (const float*)d_in[k++];
  }
  p.Wd   = (const float*)d_in[k++];
  p.bd   = (const float*)d_in[k++];
  p.mean = (const float*)d_in[k++];
  p.stdv = (const float*)d_in[k++];
  p.out  = (float*)d_out;
  p.ws   = (float*)d_ws;

  // ws layout: hbuf | xbuf | WxT/WhT x3 | WdT | barrier (1024 u32)
  size_t off = 6 * BB * UU + BB * DD;
  float* wsf = (float*)d_ws;
  const int KxDims[3] = { DD, UU, UU };
  float* WxT[3]; float* WhT[3]; float* WdT;
  for (int j = 0; j < 3; ++j) {
    WxT[j] = wsf + off; off += (size_t)GG * KxDims[j];
    WhT[j] = wsf + off; off += (size_t)GG * UU;
  }
  WdT = wsf + off; off += (size_t)DD * UU;
  off = (off + 63) & ~(size_t)63;
  unsigned* bar = (unsigned*)(wsf + off); off += 1024;
  const size_t need_bytes = off * sizeof(float);

  dim3 tb(32, 8);
  for (int j = 0; j < 3; ++j) {
    transpose_kernel<<<dim3(GG / 32, KxDims[j] / 32), tb, 0, stream>>>(
        p.Wx[j], WxT[j], KxDims[j], GG);
    transpose_kernel<<<dim3(GG / 32, UU / 32), tb, 0, stream>>>(
        p.Wh[j], WhT[j], UU, GG);
  }
  transpose_kernel<<<dim3(DD / 32, UU / 32), tb, 0, stream>>>(p.Wd, WdT, UU, DD);
  for (int j = 0; j < 3; ++j) { p.WxT[j] = WxT[j]; p.WhT[j] = WhT[j]; }
  p.WdT = WdT;
  p.bar = bar;

  hipError_t e = hipErrorUnknown;
  if (ws_size >= need_bytes) {
    bar_init_kernel<<<1, 256, 0, stream>>>(bar);
    e = hipFuncSetAttribute(reinterpret_cast<const void*>(gru_ar_buf),
                            hipFuncAttributeMaxDynamicSharedMemorySize, LDS_BYTES);
    if (e == hipSuccess) {
      void* args[] = { &p };
      e = hipLaunchCooperativeKernel((void*)gru_ar_buf, dim3(NBLK), dim3(512),
                                     args, LDS_BYTES, stream);
    }
  }
  if (e != hipSuccess) {
    (void)hipFuncSetAttribute(reinterpret_cast<const void*>(gru_ar_cg),
                              hipFuncAttributeMaxDynamicSharedMemorySize, LDS_BYTES_CG);
    void* args[] = { &p };
    (void)hipLaunchCooperativeKernel((void*)gru_ar_cg, dim3(NBLK), dim3(512),
                                     args, LDS_BYTES_CG, stream);
  }
}

// Round 14
// 6711.390 us; speedup vs baseline: 6.7253x; 6.7253x over previous
//
#include <hip/hip_runtime.h>
#include <hip/hip_cooperative_groups.h>
#include <cmath>

namespace cg = cooperative_groups;

#define BB   64      // batch
#define DD   512     // data dim
#define UU   768     // units
#define GG   2304    // 3*UU
#define TIN  64
#define TOUT 64
#define NBLK 256

// LDS layout (f32x4 units): 9 rows per matrix, row = cc*3+gate
#define OFF_WX0 0          // 9 x 128 f4
#define OFF_WH0 1152       // 9 x 192
#define OFF_WX1 2880
#define OFF_WH1 4608
#define OFF_WX2 6336
#define OFF_WH2 8064
#define OFF_H2S 9792       // dense h2 staging: 196 f4 (padded: +1 per 48)
#define LDS_F4  9988
#define LDS_BYTES    (LDS_F4 * 16)   // 159,808 B <= 163,840
#define LDS_BYTES_CG (9792 * 16)

typedef float f32x4 __attribute__((ext_vector_type(4)));
typedef float f32x2 __attribute__((ext_vector_type(2)));
typedef int   i32x4 __attribute__((ext_vector_type(4)));

// CK-style raw buffer intrinsics (compiler-tracked loads/stores; SRD bounds-check)
__device__ f32x4 buf_ld4(i32x4 srsrc, int voffset, int soffset, int aux) __asm("llvm.amdgcn.raw.buffer.load.v4f32");
__device__ float buf_ld1(i32x4 srsrc, int voffset, int soffset, int aux) __asm("llvm.amdgcn.raw.buffer.load.f32");
__device__ void  buf_st1(float data, i32x4 srsrc, int voffset, int soffset, int aux) __asm("llvm.amdgcn.raw.buffer.store.f32");

#define AUX_SC 17   // CPol SC0|SC1: bypass L1/L2, access the coherence point

__device__ __forceinline__ i32x4 make_srd(const void* base, unsigned bytes) {
  unsigned long long a = (unsigned long long)base;
  i32x4 r;
  r.x = (int)(a & 0xffffffffull);
  r.y = (int)(a >> 32);
  r.z = (int)bytes;
  r.w = 0x00020000;
  return r;
}

__device__ __forceinline__ int wsoff(const float* base, const float* q) {
  return (int)((const char*)q - (const char*)base);
}

struct P {
  const float* inputs;
  const float* Wx[3];
  const float* Wh[3];
  const float* bi[3];
  const float* br[3];
  const float* h0[3];
  const float* Wd;
  const float* bd;
  const float* mean;
  const float* stdv;
  const float* WxT[3];
  const float* WhT[3];
  const float* WdT;
  float* out;
  float* ws;
  unsigned* bar;
};

__device__ __forceinline__ float sigm(float a) { return 1.0f / (1.0f + expf(-a)); }

__device__ __forceinline__ f32x2 pkfma(f32x2 a, f32x2 b, f32x2 c) {
  return __builtin_elementwise_fma(a, b, c);
}
__device__ __forceinline__ void dot4p(f32x4 a, f32x4 b, f32x2& acc) {
  f32x2 alo = { a.x, a.y }, ahi = { a.z, a.w };
  f32x2 blo = { b.x, b.y }, bhi = { b.z, b.w };
  acc = pkfma(alo, blo, acc);
  acc = pkfma(ahi, bhi, acc);
}
__device__ __forceinline__ float dot4(f32x4 a, f32x4 b, float acc) {
  acc = fmaf(a.x, b.x, acc);
  acc = fmaf(a.y, b.y, acc);
  acc = fmaf(a.z, b.z, acc);
  acc = fmaf(a.w, b.w, acc);
  return acc;
}

// ---- fence-free two-level grid barrier (R11-proven) ----
__device__ __forceinline__ void gridbar(unsigned* bar, unsigned& epoch) {
  asm volatile("s_waitcnt vmcnt(0)" ::: "memory");
  __syncthreads();
  if (threadIdx.x == 0) {
    const unsigned next = epoch + 1;
    unsigned* leaf = bar + (blockIdx.x & 15) * 32;
    unsigned* root = bar + 512;
    unsigned* gen  = bar + 544;
    unsigned lold = __hip_atomic_fetch_add(leaf, 1u, __ATOMIC_RELAXED, __HIP_MEMORY_SCOPE_AGENT);
    if (lold == next * 16u - 1u) {
      unsigned rold = __hip_atomic_fetch_add(root, 1u, __ATOMIC_RELAXED, __HIP_MEMORY_SCOPE_AGENT);
      if (rold == next * 16u - 1u) {
        __hip_atomic_store(gen, next, __ATOMIC_RELAXED, __HIP_MEMORY_SCOPE_AGENT);
      } else {
        while (__hip_atomic_load(gen, __ATOMIC_RELAXED, __HIP_MEMORY_SCOPE_AGENT) < next)
          __builtin_amdgcn_s_sleep(1);
      }
    } else {
      while (__hip_atomic_load(gen, __ATOMIC_RELAXED, __HIP_MEMORY_SCOPE_AGENT) < next)
        __builtin_amdgcn_s_sleep(1);
    }
    asm volatile("" ::: "memory");
  }
  epoch += 1;
  __syncthreads();
}

__global__ void bar_init_kernel(unsigned* bar) {
  for (int i = threadIdx.x; i < 1024; i += 256)
    __hip_atomic_store(bar + i, 0u, __ATOMIC_RELAXED, __HIP_MEMORY_SCOPE_AGENT);
}

// ---------------- tiled transpose: dst[c][r] = src[r][c] ----------------
__global__ __launch_bounds__(256) void transpose_kernel(
    const float* __restrict__ src, float* __restrict__ dst, int R, int C) {
  __shared__ float tile[32][33];
  const int bx = blockIdx.x * 32;
  const int by = blockIdx.y * 32;
  const int tx = threadIdx.x;
  const int ty = threadIdx.y;
  #pragma unroll
  for (int i = 0; i < 32; i += 8)
    tile[ty + i][tx] = src[(size_t)(by + ty + i) * C + (bx + tx)];
  __syncthreads();
  #pragma unroll
  for (int i = 0; i < 32; i += 8)
    dst[(size_t)(bx + ty + i) * R + (by + tx)] = tile[tx][ty + i];
}

// ---- load a 24-f4 coherent row slice into a register array ----
__device__ __forceinline__ void pref_load24(i32x4 srd, int rowoff, int kq, f32x4* b) {
  #pragma unroll
  for (int t = 0; t < 24; ++t)
    b[t] = buf_ld4(srd, rowoff + (t * 8 + kq) * 16, 0, AUX_SC);
}

// ---- consume a prefetched register slice against LDS weights ----
template<int KX4>
__device__ __forceinline__ void matdot9_reg24(const f32x4* b, const f32x4* __restrict__ w,
                                              int kq, f32x2* __restrict__ acc) {
  #pragma unroll
  for (int t = 0; t < 24; ++t) {
    #pragma unroll
    for (int r = 0; r < 9; ++r)
      dot4p(b[t], w[r * KX4 + t * 8 + kq], acc[r]);
  }
}

// ---- 9-row dot, live coherent loads in rolling groups of 8 ----
template<int NT, int KX4>
__device__ __forceinline__ void matdot9_buf(i32x4 srd, int rowoff,
                                            const f32x4* __restrict__ w,
                                            int kq, f32x2* __restrict__ acc) {
  f32x4 g0[8], g1[8];
  #pragma unroll
  for (int u = 0; u < 8; ++u)
    g0[u] = buf_ld4(srd, rowoff + (u * 8 + kq) * 16, 0, AUX_SC);
  #pragma unroll
  for (int u = 0; u < 8; ++u)
    g1[u] = buf_ld4(srd, rowoff + ((8 + u) * 8 + kq) * 16, 0, AUX_SC);
  #pragma unroll
  for (int u = 0; u < 8; ++u) {
    #pragma unroll
    for (int r = 0; r < 9; ++r)
      dot4p(g0[u], w[r * KX4 + u * 8 + kq], acc[r]);
  }
  if constexpr (NT == 24) {
    #pragma unroll
    for (int u = 0; u < 8; ++u)
      g0[u] = buf_ld4(srd, rowoff + ((16 + u) * 8 + kq) * 16, 0, AUX_SC);
  }
  #pragma unroll
  for (int u = 0; u < 8; ++u) {
    #pragma unroll
    for (int r = 0; r < 9; ++r)
      dot4p(g1[u], w[r * KX4 + (8 + u) * 8 + kq], acc[r]);
  }
  if constexpr (NT == 24) {
    #pragma unroll
    for (int u = 0; u < 8; ++u) {
      #pragma unroll
      for (int r = 0; r < 9; ++r)
        dot4p(g0[u], w[r * KX4 + (16 + u) * 8 + kq], acc[r]);
    }
  }
}

// ---- plain cached path (read-only inputs tensor) ----
template<int NT, int KX4>
__device__ __forceinline__ void matdot9_pl(const float* __restrict__ rowbase,
                                           const f32x4* __restrict__ w,
                                           int kq, f32x2* __restrict__ acc) {
  const f32x4* xv = (const f32x4*)rowbase;
  #pragma unroll 2
  for (int t = 0; t < NT; ++t) {
    const int idx = t * 8 + kq;
    f32x4 v = xv[idx];
    #pragma unroll
    for (int r = 0; r < 9; ++r) dot4p(v, w[r * KX4 + idx], acc[r]);
  }
}

// ---- shared gate epilogue ----
__device__ __forceinline__ void gru_epilogue(
    const float* wsbase, i32x4 srd,
    float* __restrict__ ax, float* __restrict__ ah,
    const float* __restrict__ bi, const float* __restrict__ br,
    const float* __restrict__ hrow, float* __restrict__ hn,
    int c0, int b, int kq)
{
  #pragma unroll
  for (int r = 0; r < 9; ++r) {
    ax[r] += __shfl_xor(ax[r], 1, 8); ax[r] += __shfl_xor(ax[r], 2, 8); ax[r] += __shfl_xor(ax[r], 4, 8);
    ah[r] += __shfl_xor(ah[r], 1, 8); ah[r] += __shfl_xor(ah[r], 2, 8); ah[r] += __shfl_xor(ah[r], 4, 8);
  }
  if (kq == 0) {
    const int ho = wsoff(wsbase, hrow + c0);
    float hprev[3];
    hprev[0] = buf_ld1(srd, ho,     0, AUX_SC);
    hprev[1] = buf_ld1(srd, ho + 4, 0, AUX_SC);
    hprev[2] = buf_ld1(srd, ho + 8, 0, AUX_SC);
    const int hno = wsoff(wsbase, hn + (size_t)b * UU + c0);
    #pragma unroll
    for (int cc = 0; cc < 3; ++cc) {
      const int c = c0 + cc;
      float z  = sigm(ax[cc*3+0] + bi[c]        + ah[cc*3+0] + br[c]);
      float rr = sigm(ax[cc*3+1] + bi[c+UU]     + ah[cc*3+1] + br[c+UU]);
      float hc = tanhf(ax[cc*3+2] + bi[c+2*UU]  + rr * (ah[cc*3+2] + br[c+2*UU]));
      buf_st1(z * hprev[cc] + (1.f - z) * hc, srd, hno + cc * 4, 0, AUX_SC);
    }
  }
}

__device__ __forceinline__ void pk_reduce9(const f32x2* p, float* s) {
  #pragma unroll
  for (int r = 0; r < 9; ++r) s[r] = p[r].x + p[r].y;
}

// ---- GRU cell, live h-load version (warmup) ----
template<int NT, int KX4, bool XSC>
__device__ __forceinline__ void gru_cell_buf(
    const float* wsbase, i32x4 srd,
    const float* __restrict__ x, int xstride,
    const f32x4* __restrict__ wx, const f32x4* __restrict__ wh,
    const float* __restrict__ bi, const float* __restrict__ br,
    const float* __restrict__ hp, float* __restrict__ hn,
    int c0, int b, int kq)
{
  f32x2 axp[9], ahp[9];
  #pragma unroll
  for (int r = 0; r < 9; ++r) { axp[r] = (f32x2)0.f; ahp[r] = (f32x2)0.f; }
  const float* xrow = x + (size_t)b * xstride;
  const float* hrow = hp + (size_t)b * UU;
  if constexpr (XSC) matdot9_buf<NT, KX4>(srd, wsoff(wsbase, xrow), wx, kq, axp);
  else               matdot9_pl<NT, KX4>(xrow, wx, kq, axp);
  matdot9_buf<24, 192>(srd, wsoff(wsbase, hrow), wh, kq, ahp);
  float ax[9], ah[9];
  pk_reduce9(axp, ax);
  pk_reduce9(ahp, ah);
  gru_epilogue(wsbase, srd, ax, ah, bi, br, hrow, hn, c0, b, kq);
}

// ---- GRU cell, prefetched-h version (AR steady state) ----
template<int NT, int KX4>
__device__ __forceinline__ void gru_cell_pf(
    const float* wsbase, i32x4 srd,
    const float* __restrict__ x, int xstride,
    const f32x4* __restrict__ wx, const f32x4* __restrict__ wh,
    const float* __restrict__ bi, const float* __restrict__ br,
    const float* __restrict__ hp, float* __restrict__ hn,
    const f32x4* __restrict__ hpf,
    int c0, int b, int kq)
{
  f32x2 axp[9], ahp[9];
  #pragma unroll
  for (int r = 0; r < 9; ++r) { axp[r] = (f32x2)0.f; ahp[r] = (f32x2)0.f; }
  const float* xrow = x + (size_t)b * xstride;
  const float* hrow = hp + (size_t)b * UU;
  matdot9_reg24<192>(hpf, wh, kq, ahp);                        // consume prefetch first
  matdot9_buf<NT, KX4>(srd, wsoff(wsbase, xrow), wx, kq, axp); // fresh x, live-loaded
  float ax[9], ah[9];
  pk_reduce9(axp, ax);
  pk_reduce9(ahp, ah);
  gru_epilogue(wsbase, srd, ax, ah, bi, br, hrow, hn, c0, b, kq);
}

// ---- dense: stage padded h2-row (SC) into LDS; xbuf write is sc store ----
__device__ __forceinline__ void dense_buf(
    const float* wsbase, i32x4 srd,
    const float* __restrict__ h2, const float* __restrict__ WdT,
    const float* __restrict__ bd, const float* __restrict__ mean,
    const float* __restrict__ stdv, float* __restrict__ out,
    float* __restrict__ xbuf, f32x4* __restrict__ ldsh2,
    int s, int blk, int tid)
{
  const int bb = blk >> 2;
  const float* hrow = h2 + (size_t)bb * UU;
  if (tid < 192) {
    ldsh2[tid + tid / 48] = buf_ld4(srd, wsoff(wsbase, hrow) + tid * 16, 0, AUX_SC);
  }
  __syncthreads();
  const int dc = (blk & 3) * 128 + (tid >> 2);
  const int kq = tid & 3;
  const f32x4* hv = ldsh2 + kq * 49;
  const f32x4* w  = (const f32x4*)(WdT + (size_t)dc * UU) + kq * 48;
  f32x2 acc2 = (f32x2)0.f;
  #pragma unroll 4
  for (int i = 0; i < 48; ++i) dot4p(hv[i], w[i], acc2);
  float acc = acc2.x + acc2.y;
  acc += __shfl_xor(acc, 1, 4);
  acc += __shfl_xor(acc, 2, 4);
  if (kq == 0) {
    float val = acc + bd[dc];
    out[((size_t)bb * TOUT + s) * DD + dc] = val;
    buf_st1((val - mean[dc]) / stdv[dc], srd,
            wsoff(wsbase, xbuf + (size_t)bb * DD + dc), 0, AUX_SC);
  }
}

// ---- LDS weight staging (both kernels) ----
__device__ __forceinline__ void stage_lds(f32x4* lds4, const P& p, int c0, int tid) {
  const float* srcs[6] = { p.WxT[0], p.WhT[0], p.WxT[1], p.WhT[1], p.WxT[2], p.WhT[2] };
  const int    Ks[6]   = { DD, UU, UU, UU, UU, UU };
  const int    offs[6] = { OFF_WX0, OFF_WH0, OFF_WX1, OFF_WH1, OFF_WX2, OFF_WH2 };
  for (int m = 0; m < 6; ++m) {
    const int K4 = Ks[m] >> 2;
    for (int r = 0; r < 9; ++r) {
      const int cc = r / 3, g = r % 3;
      const f32x4* src = (const f32x4*)(srcs[m] + (size_t)(g * UU + c0 + cc) * Ks[m]);
      f32x4* dst = lds4 + offs[m] + (size_t)r * K4;
      for (int i = tid; i < K4; i += 512) dst[i] = src[i];
    }
  }
}

// =================== main: write-through exchange, fence-free barrier (R11) ===================
__global__ __launch_bounds__(512, 2) void gru_ar_buf(P p) {
  extern __shared__ f32x4 lds4[];
  const int tid = threadIdx.x, blk = blockIdx.x;
  const int b = tid >> 3, kq = tid & 7, c0 = blk * 3;

  float* hbuf = p.ws;                    // [2 slots][3 layers][BB][UU]
  float* xbuf = p.ws + 6 * BB * UU;      // [BB][DD]
  unsigned epoch = 0;
  const i32x4 srd = make_srd(p.ws, (unsigned)((6 * BB * UU + BB * DD) * sizeof(float)));

  stage_lds(lds4, p, c0, tid);

  // init: layer j initial state -> slot j&1 (write-through sc stores)
  for (int i = blk * 512 + tid; i < 3 * BB * UU; i += NBLK * 512) {
    int j = i / (BB * UU);
    int rem = i - j * (BB * UU);
    int u = rem % UU;
    int idx = (int)(((j & 1) * 3 + j) * (BB * UU) + rem);
    buf_st1(p.h0[j][u], srd, idx * 4, 0, AUX_SC);
  }
  gridbar(p.bar, epoch);

  const f32x4* wx0 = lds4 + OFF_WX0;
  const f32x4* wh0 = lds4 + OFF_WH0;
  const f32x4* wx1 = lds4 + OFF_WX1;
  const f32x4* wh1 = lds4 + OFF_WH1;
  const f32x4* wx2 = lds4 + OFF_WX2;
  const f32x4* wh2 = lds4 + OFF_WH2;
  f32x4* ldsh2 = lds4 + OFF_H2S;

  #define HBASE(sl, j) (hbuf + ((size_t)(sl) * 3 + (j)) * BB * UU)

  // ---- warmup: wavefront diagonals, one barrier per diagonal ----
  for (int d = 0; d < TIN + 2; ++d) {
    const int rs = d & 1, wsl = rs ^ 1;
    if (d < TIN) {
      gru_cell_buf<16, 128, false>(p.ws, srd, p.inputs + (size_t)d * DD, TIN * DD,
                                   wx0, wh0, p.bi[0], p.br[0],
                                   HBASE(rs, 0), HBASE(wsl, 0), c0, b, kq);
    }
    if (d >= 1 && d <= TIN) {
      gru_cell_buf<24, 192, true>(p.ws, srd, HBASE(rs, 0), UU,
                                  wx1, wh1, p.bi[1], p.br[1],
                                  HBASE(rs, 1), HBASE(wsl, 1), c0, b, kq);
    }
    if (d >= 2 && d <= TIN + 1) {
      gru_cell_buf<24, 192, true>(p.ws, srd, HBASE(rs, 1), UU,
                                  wx2, wh2, p.bi[2], p.br[2],
                                  HBASE(rs, 2), HBASE(wsl, 2), c0, b, kq);
    }
    gridbar(p.bar, epoch);
  }

  // pred0 (h2 final warmup state in slot 0) + bootstrap prefetch of h0 for s=0
  f32x4 pf[24];
  dense_buf(p.ws, srd, HBASE(0, 2), p.WdT, p.bd, p.mean, p.stdv,
            p.out, xbuf, ldsh2, 0, blk, tid);
  pref_load24(srd, wsoff(p.ws, HBASE(0, 0) + (size_t)b * UU), kq, pf);
  gridbar(p.bar, epoch);

  // ---- autoregressive: strict chain, 4 barriers per step, h-prefetched ----
  for (int s = 0; s < TOUT - 1; ++s) {
    { const int rs = s & 1;              // layer 0: x=xbuf (fresh), h prefetched
      gru_cell_pf<16, 128>(p.ws, srd, xbuf, DD, wx0, wh0, p.bi[0], p.br[0],
                           HBASE(rs, 0), HBASE(rs ^ 1, 0), pf, c0, b, kq);
      pref_load24(srd, wsoff(p.ws, HBASE((s + 1) & 1, 1) + (size_t)b * UU), kq, pf);
      gridbar(p.bar, epoch); }
    { const int rs = (s + 1) & 1;        // layer 1: x=h0(s) (fresh), h prefetched
      gru_cell_pf<24, 192>(p.ws, srd, HBASE(rs, 0), UU, wx1, wh1, p.bi[1], p.br[1],
                           HBASE(rs, 1), HBASE(rs ^ 1, 1), pf, c0, b, kq);
      pref_load24(srd, wsoff(p.ws, HBASE(s & 1, 2) + (size_t)b * UU), kq, pf);
      gridbar(p.bar, epoch); }
    { const int rs = s & 1;              // layer 2: x=h1(s) (fresh), h prefetched
      gru_cell_pf<24, 192>(p.ws, srd, HBASE(rs, 1), UU, wx2, wh2, p.bi[2], p.br[2],
                           HBASE(rs, 2), HBASE(rs ^ 1, 2), pf, c0, b, kq);
      pref_load24(srd, wsoff(p.ws, HBASE((s + 1) & 1, 0) + (size_t)b * UU), kq, pf);
      gridbar(p.bar, epoch); }
    dense_buf(p.ws, srd, HBASE((s + 1) & 1, 2), p.WdT, p.bd, p.mean, p.stdv,
              p.out, xbuf, ldsh2, s + 1, blk, tid);
    gridbar(p.bar, epoch);
  }
  #undef HBASE
}

// =================== fallback: cg-sync kernel (proven) ===================
template<int NX4T, int KX4>
__device__ __forceinline__ void gru_cell_lds(
    const float* __restrict__ x, int xstride,
    const f32x4* __restrict__ wx, const f32x4* __restrict__ wh,
    const float* __restrict__ bi, const float* __restrict__ br,
    const float* __restrict__ hp, float* __restrict__ hn,
    int c0, int b, int kq)
{
  float ax[9], ah[9];
  #pragma unroll
  for (int r = 0; r < 9; ++r) { ax[r] = 0.f; ah[r] = 0.f; }
  const f32x4* xv = (const f32x4*)(x + (size_t)b * xstride);
  #pragma unroll 2
  for (int t = 0; t < NX4T; ++t) {
    const int idx = t * 8 + kq;
    f32x4 v = xv[idx];
    #pragma unroll
    for (int r = 0; r < 9; ++r) ax[r] = dot4(v, wx[r * KX4 + idx], ax[r]);
  }
  const f32x4* hv = (const f32x4*)(hp + (size_t)b * UU);
  #pragma unroll 2
  for (int t = 0; t < 24; ++t) {
    const int idx = t * 8 + kq;
    f32x4 v = hv[idx];
    #pragma unroll
    for (int r = 0; r < 9; ++r) ah[r] = dot4(v, wh[r * 192 + idx], ah[r]);
  }
  #pragma unroll
  for (int r = 0; r < 9; ++r) {
    ax[r] += __shfl_xor(ax[r], 1, 8); ax[r] += __shfl_xor(ax[r], 2, 8); ax[r] += __shfl_xor(ax[r], 4, 8);
    ah[r] += __shfl_xor(ah[r], 1, 8); ah[r] += __shfl_xor(ah[r], 2, 8); ah[r] += __shfl_xor(ah[r], 4, 8);
  }
  #pragma unroll
  for (int cc = 0; cc < 3; ++cc) {
    const int c = c0 + cc;
    float z  = sigm(ax[cc*3+0] + bi[c]        + ah[cc*3+0] + br[c]);
    float rr = sigm(ax[cc*3+1] + bi[c+UU]     + ah[cc*3+1] + br[c+UU]);
    float hc = tanhf(ax[cc*3+2] + bi[c+2*UU]  + rr * (ah[cc*3+2] + br[c+2*UU]));
    float hprev = hp[(size_t)b * UU + c];
    if (kq == 0) hn[(size_t)b * UU + c] = z * hprev + (1.f - z) * hc;
  }
}

__device__ __forceinline__ void dense_t(
    const float* __restrict__ h2, const float* __restrict__ WdT,
    const float* __restrict__ bd, const float* __restrict__ mean,
    const float* __restrict__ stdv, float* __restrict__ out,
    float* __restrict__ xbuf, int s, int blk, int tid)
{
  const int o  = blk * 128 + (tid >> 2);
  const int bb = o >> 9;
  const int dc = o & 511;
  const int kq = tid & 3;
  const f32x4* hv = (const f32x4*)(h2 + (size_t)bb * UU) + kq * 48;
  const f32x4* w  = (const f32x4*)(WdT + (size_t)dc * UU) + kq * 48;
  float acc = 0.f;
  #pragma unroll 4
  for (int i = 0; i < 48; ++i) acc = dot4(hv[i], w[i], acc);
  acc += __shfl_xor(acc, 1, 4);
  acc += __shfl_xor(acc, 2, 4);
  if (kq == 0) {
    float val = acc + bd[dc];
    out[((size_t)bb * TOUT + s) * DD + dc] = val;
    xbuf[(size_t)bb * DD + dc] = (val - mean[dc]) / stdv[dc];
  }
}

__global__ __launch_bounds__(512, 2) void gru_ar_cg(P p) {
  cg::grid_group grid = cg::this_grid();
  extern __shared__ f32x4 lds4[];
  const int tid = threadIdx.x, blk = blockIdx.x;
  const int b = tid >> 3, kq = tid & 7, c0 = blk * 3;
  float* hbuf = p.ws;
  float* xbuf = p.ws + 6 * BB * UU;
  stage_lds(lds4, p, c0, tid);
  for (int i = blk * 512 + tid; i < 3 * BB * UU; i += NBLK * 512) {
    int j = i / (BB * UU);
    int u = i % UU;
    hbuf[i] = p.h0[j][u];
  }
  grid.sync();
  const f32x4* wx0 = lds4 + OFF_WX0; const f32x4* wh0 = lds4 + OFF_WH0;
  const f32x4* wx1 = lds4 + OFF_WX1; const f32x4* wh1 = lds4 + OFF_WH1;
  const f32x4* wx2 = lds4 + OFF_WX2; const f32x4* wh2 = lds4 + OFF_WH2;
  for (int t = 0; t < TIN + TOUT - 1; ++t) {
    const int pr = t & 1, pw = pr ^ 1;
    #pragma unroll 1
    for (int j = 0; j < 3; ++j) {
      const float* x; int xstride;
      if (j == 0) {
        if (t < TIN) { x = p.inputs + (size_t)t * DD; xstride = TIN * DD; }
        else         { x = xbuf;                       xstride = DD; }
      } else {
        x = hbuf + ((size_t)pw * 3 + (j - 1)) * BB * UU; xstride = UU;
      }
      const float* hp = hbuf + ((size_t)pr * 3 + j) * BB * UU;
      float*       hn = hbuf + ((size_t)pw * 3 + j) * BB * UU;
      if (j == 0)      gru_cell_lds<16, 128>(x, xstride, wx0, wh0, p.bi[0], p.br[0], hp, hn, c0, b, kq);
      else if (j == 1) gru_cell_lds<24, 192>(x, xstride, wx1, wh1, p.bi[1], p.br[1], hp, hn, c0, b, kq);
      else             gru_cell_lds<24, 192>(x, xstride, wx2, wh2, p.bi[2], p.br[2], hp, hn, c0, b, kq);
      grid.sync();
    }
    if (t >= TIN - 1) {
      const int s = t - (TIN - 1);
      const float* h2 = hbuf + ((size_t)pw * 3 + 2) * BB * UU;
      dense_t(h2, p.WdT, p.bd, p.mean, p.stdv, p.out, xbuf, s, blk, tid);
      grid.sync();
    }
  }
}

extern "C" void kernel_launch(void* const* d_in, const int* in_sizes, int n_in,
                              void* d_out, int out_size, void* d_ws, size_t ws_size,
                              hipStream_t stream) {
  P p;
  p.inputs = (const float*)d_in[0];
  int k = 1;
  for (int j = 0; j < 3; ++j) {
    p.Wx[j] = (const float*)d_in[k++];
    p.Wh[j] = (const float*)d_in[k++];
    p.bi[j] = (const float*)d_in[k++];
    p.br[j] = (const float*)d_in[k++];
    p.h0[j] = (const float*)d_in[k++];
  }
  p.Wd   = (const float*)d_in[k++];
  p.bd   = (const float*)d_in[k++];
  p.mean = (const float*)d_in[k++];
  p.stdv = (const float*)d_in[k++];
  p.out  = (float*)d_out;
  p.ws   = (float*)d_ws;

  // ws layout: hbuf | xbuf | WxT/WhT x3 | WdT | barrier (1024 u32)
  size_t off = 6 * BB * UU + BB * DD;
  float* wsf = (float*)d_ws;
  const int KxDims[3] = { DD, UU, UU };
  float* WxT[3]; float* WhT[3]; float* WdT;
  for (int j = 0; j < 3; ++j) {
    WxT[j] = wsf + off; off += (size_t)GG * KxDims[j];
    WhT[j] = wsf + off; off += (size_t)GG * UU;
  }
  WdT = wsf + off; off += (size_t)DD * UU;
  off = (off + 63) & ~(size_t)63;
  unsigned* bar = (unsigned*)(wsf + off); off += 1024;
  const size_t need_bytes = off * sizeof(float);

  dim3 tb(32, 8);
  for (int j = 0; j < 3; ++j) {
    transpose_kernel<<<dim3(GG / 32, KxDims[j] / 32), tb, 0, stream>>>(
        p.Wx[j], WxT[j], KxDims[j], GG);
    transpose_kernel<<<dim3(GG / 32, UU / 32), tb, 0, stream>>>(
        p.Wh[j], WhT[j], UU, GG);
  }
  transpose_kernel<<<dim3(DD / 32, UU / 32), tb, 0, stream>>>(p.Wd, WdT, UU, DD);
  for (int j = 0; j < 3; ++j) { p.WxT[j] = WxT[j]; p.WhT[j] = WhT[j]; }
  p.WdT = WdT;
  p.bar = bar;

  hipError_t e = hipErrorUnknown;
  if (ws_size >= need_bytes) {
    bar_init_kernel<<<1, 256, 0, stream>>>(bar);
    e = hipFuncSetAttribute(reinterpret_cast<const void*>(gru_ar_buf),
                            hipFuncAttributeMaxDynamicSharedMemorySize, LDS_BYTES);
    if (e == hipSuccess) {
      void* args[] = { &p };
      e = hipLaunchCooperativeKernel((void*)gru_ar_buf, dim3(NBLK), dim3(512),
                                     args, LDS_BYTES, stream);
    }
  }
  if (e != hipSuccess) {
    (void)hipFuncSetAttribute(reinterpret_cast<const void*>(gru_ar_cg),
                              hipFuncAttributeMaxDynamicSharedMemorySize, LDS_BYTES_CG);
    void* args[] = { &p };
    (void)hipLaunchCooperativeKernel((void*)gru_ar_cg, dim3(NBLK), dim3(512),
                                     args, LDS_BYTES_CG, stream);
  }
}